// Round 13
// baseline (271.138 us; speedup 1.0000x reference)
//
#include <hip/hip_runtime.h>

#define IN_DIM 128
#define RB_SHIFT 10 // 1024 nodes per dest-range
#define RB 1024
#define NBMAX 128   // max ranges (N <= 128K)
#define MAXBIN 16384 // capacity per range bin region (mean ~12.3K)
#define PCH 2048    // edges per k_part block

typedef short bf16x8 __attribute__((ext_vector_type(8)));
typedef float f32x4  __attribute__((ext_vector_type(4)));

__device__ __forceinline__ float relu(float v) { return v > 0.f ? v : 0.f; }

// fp32 -> bf16 round-to-nearest-even
__device__ __forceinline__ unsigned short f2bf(float f) {
    unsigned u = __float_as_uint(f);
    u += 0x7FFFu + ((u >> 16) & 1u);
    return (unsigned short)(u >> 16);
}
__device__ __forceinline__ float bflo(unsigned u) { return __uint_as_float(u << 16); }
__device__ __forceinline__ float bfhi(unsigned u) { return __uint_as_float(u & 0xFFFF0000u); }

// ---- weight repack into MFMA B-frag order (+ binCursor init, block 0) ----
__global__ __launch_bounds__(256) void k_wprep(const float* __restrict__ W1a,
                                               const float* __restrict__ W2a,
                                               const float* __restrict__ W1b,
                                               const float* __restrict__ W2b,
                                               unsigned short* __restrict__ Wt,
                                               int* __restrict__ binCursor, int NR) {
    if (blockIdx.x == 0 && threadIdx.x < NR) binCursor[threadIdx.x] = threadIdx.x * MAXBIN;
    const int t = blockIdx.x * 256 + threadIdx.x;   // (layer,kc,c,lane)
    if (t >= 2 * 4 * 8 * 64) return;
    const int lane = t & 63;
    const int c = (t >> 6) & 7;
    const int kc = (t >> 9) & 3;
    const int layer = t >> 11;
    const int col = c * 16 + (lane & 15);
    const int k0 = kc * 32 + (lane >> 4) * 8;
    const float* W1 = layer ? W1b : W1a;
    const float* W2 = layer ? W2b : W2a;
    const float* src = (col < 64) ? (W1 + col) : (W2 + (col - 64));
    unsigned short v[8];
#pragma unroll
    for (int j = 0; j < 8; j++) v[j] = f2bf(src[(size_t)(k0 + j) * 64]);
    *(ushort4*)(Wt + (size_t)t * 8) = make_ushort4(v[0], v[1], v[2], v[3]);
    *(ushort4*)(Wt + (size_t)t * 8 + 4) = make_ushort4(v[4], v[5], v[6], v[7]);
}

// ---- phase 1: partition edges into dest-ranges; entry packed (row<<10)|li ----
__global__ __launch_bounds__(256) void k_part(const int* __restrict__ row,
                                              const int* __restrict__ col,
                                              int* __restrict__ binCursor,
                                              int* __restrict__ part, int E) {
    __shared__ int lcur[NBMAX], gbase[NBMAX];
    const int tid = threadIdx.x;
    const int e0 = blockIdx.x * PCH;
    const int cnt = min(PCH, E - e0);
    if (tid < NBMAX) lcur[tid] = 0;
    __syncthreads();
    int rr[8], cc[8], pp[8];
    if (cnt == PCH) {
#pragma unroll
        for (int h = 0; h < 2; h++) {
            const int4 c4 = *(const int4*)(col + e0 + h * 1024 + tid * 4);
            const int4 r4 = *(const int4*)(row + e0 + h * 1024 + tid * 4);
            cc[h * 4 + 0] = c4.x; cc[h * 4 + 1] = c4.y;
            cc[h * 4 + 2] = c4.z; cc[h * 4 + 3] = c4.w;
            rr[h * 4 + 0] = r4.x; rr[h * 4 + 1] = r4.y;
            rr[h * 4 + 2] = r4.z; rr[h * 4 + 3] = r4.w;
        }
    } else {
#pragma unroll
        for (int j = 0; j < 8; j++) {
            const int e = e0 + j * 256 + tid;
            if (e < e0 + cnt) { rr[j] = row[e]; cc[j] = col[e]; }
            else cc[j] = -1;
        }
    }
#pragma unroll
    for (int j = 0; j < 8; j++)
        if (cc[j] >= 0) pp[j] = atomicAdd(&lcur[cc[j] >> RB_SHIFT], 1);
    __syncthreads();
    if (tid < NBMAX && lcur[tid] > 0)
        gbase[tid] = atomicAdd(&binCursor[tid], lcur[tid]);
    __syncthreads();
#pragma unroll
    for (int j = 0; j < 8; j++)
        if (cc[j] >= 0)
            part[gbase[cc[j] >> RB_SHIFT] + pp[j]] =
                (rr[j] << RB_SHIFT) | (cc[j] & (RB - 1));
}

// ---- phase 2 (merged): per-range histogram + local scan + placement ----
__global__ __launch_bounds__(256) void k_csr(const int* __restrict__ binCursor,
                                             const int* __restrict__ part,
                                             int* __restrict__ degi,
                                             float* __restrict__ dinv,
                                             int* __restrict__ start,
                                             int* __restrict__ rs, int N) {
    __shared__ int cnt[RB];
    __shared__ int psum[256];
    const int b = blockIdx.x;
    const int lo = b << RB_SHIFT;
    const int tid = threadIdx.x;
    for (int i = tid; i < RB; i += 256) cnt[i] = 0;
    __syncthreads();
    const int base = b * MAXBIN;
    const int tot = binCursor[b] - base;
    for (int i = tid; i < tot; i += 256)
        atomicAdd(&cnt[part[base + i] & (RB - 1)], 1);
    __syncthreads();
    const int i0 = tid * 4;
    const int c0 = cnt[i0], c1 = cnt[i0 + 1], c2 = cnt[i0 + 2], c3 = cnt[i0 + 3];
    const int s = c0 + c1 + c2 + c3;
    psum[tid] = s;
    __syncthreads();
    for (int off = 1; off < 256; off <<= 1) {
        int t = (tid >= off) ? psum[tid - off] : 0;
        __syncthreads();
        psum[tid] += t;
        __syncthreads();
    }
    const int e = psum[tid] - s;   // exclusive
    const int offs[4] = {e, e + c0, e + c0 + c1, e + c0 + c1 + c2};
    const int cs[4] = {c0, c1, c2, c3};
#pragma unroll
    for (int j = 0; j < 4; j++) {
        const int n = lo + i0 + j;
        if (n < N) {
            degi[n] = cs[j];
            start[n] = base + offs[j];
            dinv[n] = cs[j] > 0 ? rsqrtf((float)cs[j]) : 0.f;
        }
        cnt[i0 + j] = base + offs[j];   // becomes LDS cursor
    }
    __syncthreads();
    for (int i = tid; i < tot; i += 256) {
        const int v = part[base + i];
        const int pos = atomicAdd(&cnt[v & (RB - 1)], 1);
        rs[pos] = v >> RB_SHIFT;
    }
}

// ---- layer-1 MFMA dual GEMM: x1 = relu(X@fcw+fcb) bf16, h1' = (X@c1w)*dinv bf16 ----
__global__ __launch_bounds__(256) void k_gemm1(const float* __restrict__ XF,
                                               const unsigned short* __restrict__ Wt,
                                               const float* __restrict__ B1,
                                               const float* __restrict__ dinv,
                                               unsigned short* __restrict__ O1b,
                                               unsigned short* __restrict__ O2,
                                               int N) {
    const int tid = threadIdx.x;
    const int wave = tid >> 6;
    const int lane = tid & 63;
    const int quad = lane >> 4;
    const int lm = lane & 15;
    const int n0 = blockIdx.x * 64 + wave * 16;
    if (n0 >= N) return;
    const int nrow = min(n0 + lm, N - 1);

    f32x4 acc[8];
#pragma unroll
    for (int c = 0; c < 8; c++) acc[c] = (f32x4){0.f, 0.f, 0.f, 0.f};

#pragma unroll
    for (int kc = 0; kc < 4; kc++) {
        const int k0 = kc * 32 + quad * 8;
        const float* s = XF + (size_t)nrow * IN_DIM + k0;
        const float4 q0 = *(const float4*)s;
        const float4 q1 = *(const float4*)(s + 4);
        bf16x8 a;
        a[0] = (short)f2bf(q0.x); a[1] = (short)f2bf(q0.y);
        a[2] = (short)f2bf(q0.z); a[3] = (short)f2bf(q0.w);
        a[4] = (short)f2bf(q1.x); a[5] = (short)f2bf(q1.y);
        a[6] = (short)f2bf(q1.z); a[7] = (short)f2bf(q1.w);
#pragma unroll
        for (int c = 0; c < 8; c++) {
            const bf16x8 b = *(const bf16x8*)(Wt + (size_t)((kc * 8 + c) * 64 + lane) * 8);
            acc[c] = __builtin_amdgcn_mfma_f32_16x16x32_bf16(a, b, acc[c], 0, 0, 0);
        }
    }

    const int nb = n0 + quad * 4;
    float dvv[4];
#pragma unroll
    for (int r = 0; r < 4; r++) dvv[r] = (nb + r < N) ? dinv[nb + r] : 0.f;
#pragma unroll
    for (int c = 0; c < 4; c++) {
        const int col = c * 16 + lm;
        const float b = B1[col];
#pragma unroll
        for (int r = 0; r < 4; r++) {
            const int n = nb + r;
            if (n < N) O1b[(size_t)n * 64 + col] = f2bf(relu(acc[c][r] + b));
        }
    }
#pragma unroll
    for (int c = 4; c < 8; c++) {
        const int col = (c - 4) * 16 + lm;
#pragma unroll
        for (int r = 0; r < 4; r++) {
            const int n = nb + r;
            if (n < N) O2[(size_t)n * 64 + col] = f2bf(acc[c][r] * dvv[r]);
        }
    }
}

#define ACCA(u)                                                          \
    a0 += bflo(u.x); a1 += bfhi(u.x); a2 += bflo(u.y); a3 += bfhi(u.y);  \
    a4 += bflo(u.z); a5 += bfhi(u.z); a6 += bflo(u.w); a7 += bfhi(u.w);
#define ACCB(u)                                                          \
    b0 += bflo(u.x); b1 += bfhi(u.x); b2 += bflo(u.y); b3 += bfhi(u.y);  \
    b4 += bflo(u.z); b5 += bfhi(u.z); b6 += bflo(u.w); b7 += bfhi(u.w);

// ---- FUSED gather1 + gemm2, dual-destination phase A ----
// Each 8-lane group gathers TWO dests (di, di+32): fused main loop issues 8
// independent H-row loads per group (round-12: 4 in flight, latency-bound).
// Phase B: two 32-node MFMA tiles from LDS x2 + global x1bf.
__global__ __launch_bounds__(256) void k_gfuse(const int* __restrict__ start,
                                               const int* __restrict__ degi,
                                               const int* __restrict__ rs,
                                               const unsigned short* __restrict__ H,
                                               const float* __restrict__ dinv,
                                               const float* __restrict__ CB,
                                               const unsigned short* __restrict__ X1B,
                                               const unsigned short* __restrict__ Wt,
                                               const float* __restrict__ B1,
                                               unsigned short* __restrict__ X5B,
                                               unsigned short* __restrict__ H2,
                                               int N) {
    __shared__ __align__(16) unsigned short x2s[64][72];
    const int tid = threadIdx.x;
    const int l = tid & 7;                 // feats 8l..8l+7
    const int di = tid >> 3;               // 0..31
    const int d0 = blockIdx.x * 64 + di;
    const int d1 = d0 + 32;

    float a0 = 0.f, a1 = 0.f, a2 = 0.f, a3 = 0.f;
    float a4 = 0.f, a5 = 0.f, a6 = 0.f, a7 = 0.f;
    float b0 = 0.f, b1 = 0.f, b2 = 0.f, b3 = 0.f;
    float b4 = 0.f, b5 = 0.f, b6 = 0.f, b7 = 0.f;
    int s0 = 1, e0 = 0, s1 = 1, e1 = 0;
    if (d0 < N) { s0 = start[d0]; e0 = s0 + degi[d0]; }
    if (d1 < N) { s1 = start[d1]; e1 = s1 + degi[d1]; }
    while (s0 + 3 < e0 && s1 + 3 < e1) {
        const int4 ea = *(const int4*)(rs + s0);
        const int4 eb = *(const int4*)(rs + s1);
        const uint4 u0 = *(const uint4*)(H + (size_t)ea.x * 64 + l * 8);
        const uint4 u1 = *(const uint4*)(H + (size_t)ea.y * 64 + l * 8);
        const uint4 u2 = *(const uint4*)(H + (size_t)ea.z * 64 + l * 8);
        const uint4 u3 = *(const uint4*)(H + (size_t)ea.w * 64 + l * 8);
        const uint4 v0 = *(const uint4*)(H + (size_t)eb.x * 64 + l * 8);
        const uint4 v1 = *(const uint4*)(H + (size_t)eb.y * 64 + l * 8);
        const uint4 v2 = *(const uint4*)(H + (size_t)eb.z * 64 + l * 8);
        const uint4 v3 = *(const uint4*)(H + (size_t)eb.w * 64 + l * 8);
        ACCA(u0) ACCA(u1) ACCA(u2) ACCA(u3)
        ACCB(v0) ACCB(v1) ACCB(v2) ACCB(v3)
        s0 += 4; s1 += 4;
    }
    while (s0 + 3 < e0) {
        const int4 ea = *(const int4*)(rs + s0);
        const uint4 u0 = *(const uint4*)(H + (size_t)ea.x * 64 + l * 8);
        const uint4 u1 = *(const uint4*)(H + (size_t)ea.y * 64 + l * 8);
        const uint4 u2 = *(const uint4*)(H + (size_t)ea.z * 64 + l * 8);
        const uint4 u3 = *(const uint4*)(H + (size_t)ea.w * 64 + l * 8);
        ACCA(u0) ACCA(u1) ACCA(u2) ACCA(u3)
        s0 += 4;
    }
    while (s1 + 3 < e1) {
        const int4 eb = *(const int4*)(rs + s1);
        const uint4 v0 = *(const uint4*)(H + (size_t)eb.x * 64 + l * 8);
        const uint4 v1 = *(const uint4*)(H + (size_t)eb.y * 64 + l * 8);
        const uint4 v2 = *(const uint4*)(H + (size_t)eb.z * 64 + l * 8);
        const uint4 v3 = *(const uint4*)(H + (size_t)eb.w * 64 + l * 8);
        ACCB(v0) ACCB(v1) ACCB(v2) ACCB(v3)
        s1 += 4;
    }
    for (; s0 < e0; ++s0) {
        const uint4 u0 = *(const uint4*)(H + (size_t)rs[s0] * 64 + l * 8);
        ACCA(u0)
    }
    for (; s1 < e1; ++s1) {
        const uint4 v0 = *(const uint4*)(H + (size_t)rs[s1] * 64 + l * 8);
        ACCB(v0)
    }
    const float4 cba = *(const float4*)(CB + l * 8);
    const float4 cbb = *(const float4*)(CB + l * 8 + 4);
    {
        uint4 ov = make_uint4(0u, 0u, 0u, 0u);
        if (d0 < N) {
            const float dd = dinv[d0];
            ov.x = (unsigned)f2bf(relu(dd * a0 + cba.x)) |
                   ((unsigned)f2bf(relu(dd * a1 + cba.y)) << 16);
            ov.y = (unsigned)f2bf(relu(dd * a2 + cba.z)) |
                   ((unsigned)f2bf(relu(dd * a3 + cba.w)) << 16);
            ov.z = (unsigned)f2bf(relu(dd * a4 + cbb.x)) |
                   ((unsigned)f2bf(relu(dd * a5 + cbb.y)) << 16);
            ov.w = (unsigned)f2bf(relu(dd * a6 + cbb.z)) |
                   ((unsigned)f2bf(relu(dd * a7 + cbb.w)) << 16);
        }
        *(uint4*)&x2s[di][l * 8] = ov;
    }
    {
        uint4 ov = make_uint4(0u, 0u, 0u, 0u);
        if (d1 < N) {
            const float dd = dinv[d1];
            ov.x = (unsigned)f2bf(relu(dd * b0 + cba.x)) |
                   ((unsigned)f2bf(relu(dd * b1 + cba.y)) << 16);
            ov.y = (unsigned)f2bf(relu(dd * b2 + cba.z)) |
                   ((unsigned)f2bf(relu(dd * b3 + cba.w)) << 16);
            ov.z = (unsigned)f2bf(relu(dd * b4 + cbb.x)) |
                   ((unsigned)f2bf(relu(dd * b5 + cbb.y)) << 16);
            ov.w = (unsigned)f2bf(relu(dd * b6 + cbb.z)) |
                   ((unsigned)f2bf(relu(dd * b7 + cbb.w)) << 16);
        }
        *(uint4*)&x2s[di + 32][l * 8] = ov;
    }
    __syncthreads();

    // phase B: two 32-node tiles
    const int wave = tid >> 6;
    const int lane = tid & 63;
    const int quad = lane >> 4;
    const int lm = lane & 15;
    const int nh = (wave >> 1) * 16;
    const int cb4 = (wave & 1) * 4;
#pragma unroll
    for (int t = 0; t < 2; t++) {
        const int n0 = blockIdx.x * 64 + t * 32 + nh;
        if (n0 >= N) break;
        const int nrow = min(n0 + lm, N - 1);
        f32x4 acc[4];
#pragma unroll
        for (int c = 0; c < 4; c++) acc[c] = (f32x4){0.f, 0.f, 0.f, 0.f};
#pragma unroll
        for (int kc = 0; kc < 4; kc++) {
            bf16x8 a;
            if (kc < 2) {
                a = *(const bf16x8*)(X1B + (size_t)nrow * 64 + kc * 32 + quad * 8);
            } else {
                a = *(const bf16x8*)&x2s[t * 32 + nh + lm][(kc - 2) * 32 + quad * 8];
            }
#pragma unroll
            for (int c = 0; c < 4; c++) {
                const bf16x8 b =
                    *(const bf16x8*)(Wt + (size_t)((kc * 8 + cb4 + c) * 64 + lane) * 8);
                acc[c] = __builtin_amdgcn_mfma_f32_16x16x32_bf16(a, b, acc[c], 0, 0, 0);
            }
        }
        const int nb = n0 + quad * 4;
        if (cb4 == 0) {
#pragma unroll
            for (int c = 0; c < 4; c++) {
                const int col = c * 16 + lm;
                const float b = B1[col];
#pragma unroll
                for (int r = 0; r < 4; r++) {
                    const int n = nb + r;
                    if (n < N) X5B[(size_t)n * 64 + col] = f2bf(relu(acc[c][r] + b));
                }
            }
        } else {
            float dvv[4];
#pragma unroll
            for (int r = 0; r < 4; r++) dvv[r] = (nb + r < N) ? dinv[nb + r] : 0.f;
#pragma unroll
            for (int c = 0; c < 4; c++) {
                const int col = c * 16 + lm;
#pragma unroll
                for (int r = 0; r < 4; r++) {
                    const int n = nb + r;
                    if (n < N) H2[(size_t)n * 64 + col] = f2bf(acc[c][r] * dvv[r]);
                }
            }
        }
    }
}

// ---- gather2 + fused combine/projections, dual-destination ----
__global__ __launch_bounds__(256) void k_gather2(const int* __restrict__ start,
                                                 const int* __restrict__ degi,
                                                 const int* __restrict__ rs,
                                                 const unsigned short* __restrict__ H,
                                                 const float* __restrict__ dinv,
                                                 const float* __restrict__ CB,
                                                 const unsigned short* __restrict__ X5B,
                                                 const float* __restrict__ FC2W,
                                                 const float* __restrict__ FC2B,
                                                 const float* __restrict__ C3W,
                                                 const float* __restrict__ C3B,
                                                 float* __restrict__ H3,
                                                 float* __restrict__ OUT, int N) {
    const int tid = threadIdx.x;
    const int l = tid & 7;
    const int di = tid >> 3;
    const int d0 = blockIdx.x * 64 + di;
    const int d1 = d0 + 32;

    float a0 = 0.f, a1 = 0.f, a2 = 0.f, a3 = 0.f;
    float a4 = 0.f, a5 = 0.f, a6 = 0.f, a7 = 0.f;
    float b0 = 0.f, b1 = 0.f, b2 = 0.f, b3 = 0.f;
    float b4 = 0.f, b5 = 0.f, b6 = 0.f, b7 = 0.f;
    int s0 = 1, e0 = 0, s1 = 1, e1 = 0;
    if (d0 < N) { s0 = start[d0]; e0 = s0 + degi[d0]; }
    if (d1 < N) { s1 = start[d1]; e1 = s1 + degi[d1]; }
    while (s0 + 3 < e0 && s1 + 3 < e1) {
        const int4 ea = *(const int4*)(rs + s0);
        const int4 eb = *(const int4*)(rs + s1);
        const uint4 u0 = *(const uint4*)(H + (size_t)ea.x * 64 + l * 8);
        const uint4 u1 = *(const uint4*)(H + (size_t)ea.y * 64 + l * 8);
        const uint4 u2 = *(const uint4*)(H + (size_t)ea.z * 64 + l * 8);
        const uint4 u3 = *(const uint4*)(H + (size_t)ea.w * 64 + l * 8);
        const uint4 v0 = *(const uint4*)(H + (size_t)eb.x * 64 + l * 8);
        const uint4 v1 = *(const uint4*)(H + (size_t)eb.y * 64 + l * 8);
        const uint4 v2 = *(const uint4*)(H + (size_t)eb.z * 64 + l * 8);
        const uint4 v3 = *(const uint4*)(H + (size_t)eb.w * 64 + l * 8);
        ACCA(u0) ACCA(u1) ACCA(u2) ACCA(u3)
        ACCB(v0) ACCB(v1) ACCB(v2) ACCB(v3)
        s0 += 4; s1 += 4;
    }
    while (s0 + 3 < e0) {
        const int4 ea = *(const int4*)(rs + s0);
        const uint4 u0 = *(const uint4*)(H + (size_t)ea.x * 64 + l * 8);
        const uint4 u1 = *(const uint4*)(H + (size_t)ea.y * 64 + l * 8);
        const uint4 u2 = *(const uint4*)(H + (size_t)ea.z * 64 + l * 8);
        const uint4 u3 = *(const uint4*)(H + (size_t)ea.w * 64 + l * 8);
        ACCA(u0) ACCA(u1) ACCA(u2) ACCA(u3)
        s0 += 4;
    }
    while (s1 + 3 < e1) {
        const int4 eb = *(const int4*)(rs + s1);
        const uint4 v0 = *(const uint4*)(H + (size_t)eb.x * 64 + l * 8);
        const uint4 v1 = *(const uint4*)(H + (size_t)eb.y * 64 + l * 8);
        const uint4 v2 = *(const uint4*)(H + (size_t)eb.z * 64 + l * 8);
        const uint4 v3 = *(const uint4*)(H + (size_t)eb.w * 64 + l * 8);
        ACCB(v0) ACCB(v1) ACCB(v2) ACCB(v3)
        s1 += 4;
    }
    for (; s0 < e0; ++s0) {
        const uint4 u0 = *(const uint4*)(H + (size_t)rs[s0] * 64 + l * 8);
        ACCA(u0)
    }
    for (; s1 < e1; ++s1) {
        const uint4 v0 = *(const uint4*)(H + (size_t)rs[s1] * 64 + l * 8);
        ACCB(v0)
    }
    const float4 cba = *(const float4*)(CB + l * 8);
    const float4 cbb = *(const float4*)(CB + l * 8 + 4);
    const float4 w9a = *(const float4*)(FC2W + l * 8);
    const float4 w9b = *(const float4*)(FC2W + l * 8 + 4);
    const float4 wXa = *(const float4*)(C3W + l * 8);
    const float4 wXb = *(const float4*)(C3W + l * 8 + 4);
#pragma unroll
    for (int h = 0; h < 2; h++) {
        const int d = h ? d1 : d0;
        if (d >= N) continue;
        const float dd = dinv[d];
        const float g0 = h ? b0 : a0, g1 = h ? b1 : a1, g2 = h ? b2 : a2, g3 = h ? b3 : a3;
        const float g4 = h ? b4 : a4, g5 = h ? b5 : a5, g6 = h ? b6 : a6, g7 = h ? b7 : a7;
        const uint4 xv = *(const uint4*)(X5B + (size_t)d * 64 + l * 8);
        const float v0 = bflo(xv.x) + relu(dd * g0 + cba.x);
        const float v1 = bfhi(xv.x) + relu(dd * g1 + cba.y);
        const float v2 = bflo(xv.y) + relu(dd * g2 + cba.z);
        const float v3 = bfhi(xv.y) + relu(dd * g3 + cba.w);
        const float v4 = bflo(xv.z) + relu(dd * g4 + cbb.x);
        const float v5 = bfhi(xv.z) + relu(dd * g5 + cbb.y);
        const float v6 = bflo(xv.w) + relu(dd * g6 + cbb.z);
        const float v7 = bfhi(xv.w) + relu(dd * g7 + cbb.w);
        float p9 = v0 * w9a.x + v1 * w9a.y + v2 * w9a.z + v3 * w9a.w
                 + v4 * w9b.x + v5 * w9b.y + v6 * w9b.z + v7 * w9b.w;
        float p10 = v0 * wXa.x + v1 * wXa.y + v2 * wXa.z + v3 * wXa.w
                  + v4 * wXb.x + v5 * wXb.y + v6 * wXb.z + v7 * wXb.w;
#pragma unroll
        for (int m = 1; m < 8; m <<= 1) {
            p9 += __shfl_xor(p9, m, 64);
            p10 += __shfl_xor(p10, m, 64);
        }
        if (l == 0) {
            OUT[d] = p9 + FC2B[0] + C3B[0];
            H3[d] = p10 * dd;   // pre-scale by dinv[row] for gather1f
        }
    }
}
#undef ACCA
#undef ACCB

// ---- final CSR gather, 1 feature (H3 pre-scaled; ×dinv[d] at end) ----
__global__ __launch_bounds__(256) void k_gather1f(const int* __restrict__ start,
                                                  const int* __restrict__ degi,
                                                  const int* __restrict__ rs,
                                                  const float* __restrict__ H3,
                                                  const float* __restrict__ dinv,
                                                  float* __restrict__ OUT, int N) {
    const int d = blockIdx.x * 256 + threadIdx.x;
    if (d >= N) return;
    int s = start[d];
    const int e2 = s + degi[d];
    float acc = 0.f;
    for (; s + 3 < e2; s += 4) {
        const int4 e4 = *(const int4*)(rs + s);
        acc += H3[e4.x] + H3[e4.y] + H3[e4.z] + H3[e4.w];
    }
    for (; s < e2; ++s) acc += H3[rs[s]];
    OUT[d] += acc * dinv[d];
}

extern "C" void kernel_launch(void* const* d_in, const int* in_sizes, int n_in,
                              void* d_out, int out_size, void* d_ws, size_t ws_size,
                              hipStream_t stream) {
    const float* x    = (const float*)d_in[0];
    const float* fcw  = (const float*)d_in[1];
    const float* fcb  = (const float*)d_in[2];
    const float* c1w  = (const float*)d_in[3];
    const float* c1b  = (const float*)d_in[4];
    const float* f1w  = (const float*)d_in[5];
    const float* f1b  = (const float*)d_in[6];
    const float* c2w  = (const float*)d_in[7];
    const float* c2b  = (const float*)d_in[8];
    const float* f2w  = (const float*)d_in[9];
    const float* f2b  = (const float*)d_in[10];
    const float* c3w  = (const float*)d_in[11];
    const float* c3b  = (const float*)d_in[12];
    const int*   ei   = (const int*)d_in[13];

    const int N = in_sizes[0] / IN_DIM;
    const int E = in_sizes[13] / 2;
    const int* row = ei;
    const int* col = ei + E;
    float* out = (float*)d_out;

    const int NR = (N + RB - 1) >> RB_SHIFT;

    const size_t Npad = ((size_t)N + 127) & ~(size_t)127;
    const size_t NF = (size_t)N * 64;
    const size_t REG = (size_t)NR * MAXBIN;
    int*   binCur = (int*)d_ws;                          // NBMAX
    int*   degi   = binCur + NBMAX;                      // N
    float* dinv   = (float*)(degi + Npad);               // N
    int*   start  = (int*)(dinv + Npad);                 // N
    unsigned short* Wt = (unsigned short*)(start + Npad);// 2*16384 bf16
    int*   part   = (int*)(Wt + 2 * 16384);              // REG int (packed)
    int*   rs     = part + REG;                          // REG int
    unsigned short* x1bf = (unsigned short*)(rs + REG);  // N*64 bf16
    unsigned short* h1   = x1bf + NF;                    // N*64 bf16
    unsigned short* h2   = h1 + NF;                      // N*64 bf16 (no alias: gfuse race)
    unsigned short* x5b  = h2 + NF;                      // N*64 bf16
    float* h3     = (float*)(x5b + NF);                  // N f32 (pre-scaled)

    const int gN = (N + 255) / 256;
    const int gG = (N + 63) / 64;
    const int gF = (N + 63) / 64;
    const int gP = (E + PCH - 1) / PCH;

    // --- CSR build + weight repack ---
    k_wprep<<<16, 256, 0, stream>>>(fcw, c1w, f1w, c2w, Wt, binCur, NR);
    k_part<<<gP, 256, 0, stream>>>(row, col, binCur, part, E);
    k_csr<<<NR, 256, 0, stream>>>(binCur, part, degi, dinv, start, rs, N);

    // --- layer 1 ---
    k_gemm1<<<gG, 256, 0, stream>>>(x, Wt, fcb, dinv, x1bf, h1, N);

    // --- gather1 + layer-2 GEMM fused (64 dests/block, dual-dest phase A) ---
    k_gfuse<<<gF, 256, 0, stream>>>(start, degi, rs, h1, dinv, c1b,
                                    x1bf, Wt + 16384, f1b, x5b, h2, N);

    // --- layer 3 (combine fused into gather2, dual-dest) ---
    k_gather2<<<gF, 256, 0, stream>>>(start, degi, rs, h2, dinv, c2b, x5b,
                                      f2w, f2b, c3w, c3b, h3, out, N);
    k_gather1f<<<gN, 256, 0, stream>>>(start, degi, rs, h3, dinv, out, N);
}

// Round 14
// 251.943 us; speedup vs baseline: 1.0762x; 1.0762x over previous
//
#include <hip/hip_runtime.h>

#define IN_DIM 128
#define RB_SHIFT 10 // 1024 nodes per dest-range
#define RB 1024
#define NBMAX 128   // max ranges (N <= 128K)
#define MAXBIN 16384 // capacity per range bin region (mean ~12.3K)
#define PCH 2048    // edges per k_part block

typedef short bf16x8 __attribute__((ext_vector_type(8)));
typedef float f32x4  __attribute__((ext_vector_type(4)));

__device__ __forceinline__ float relu(float v) { return v > 0.f ? v : 0.f; }

// fp32 -> bf16 round-to-nearest-even
__device__ __forceinline__ unsigned short f2bf(float f) {
    unsigned u = __float_as_uint(f);
    u += 0x7FFFu + ((u >> 16) & 1u);
    return (unsigned short)(u >> 16);
}
__device__ __forceinline__ float bflo(unsigned u) { return __uint_as_float(u << 16); }
__device__ __forceinline__ float bfhi(unsigned u) { return __uint_as_float(u & 0xFFFF0000u); }

// ---- weight repack into MFMA B-frag order (+ binCursor init, block 0) ----
__global__ __launch_bounds__(256) void k_wprep(const float* __restrict__ W1a,
                                               const float* __restrict__ W2a,
                                               const float* __restrict__ W1b,
                                               const float* __restrict__ W2b,
                                               unsigned short* __restrict__ Wt,
                                               int* __restrict__ binCursor, int NR) {
    if (blockIdx.x == 0 && threadIdx.x < NR) binCursor[threadIdx.x] = threadIdx.x * MAXBIN;
    const int t = blockIdx.x * 256 + threadIdx.x;   // (layer,kc,c,lane)
    if (t >= 2 * 4 * 8 * 64) return;
    const int lane = t & 63;
    const int c = (t >> 6) & 7;
    const int kc = (t >> 9) & 3;
    const int layer = t >> 11;
    const int col = c * 16 + (lane & 15);
    const int k0 = kc * 32 + (lane >> 4) * 8;
    const float* W1 = layer ? W1b : W1a;
    const float* W2 = layer ? W2b : W2a;
    const float* src = (col < 64) ? (W1 + col) : (W2 + (col - 64));
    unsigned short v[8];
#pragma unroll
    for (int j = 0; j < 8; j++) v[j] = f2bf(src[(size_t)(k0 + j) * 64]);
    *(ushort4*)(Wt + (size_t)t * 8) = make_ushort4(v[0], v[1], v[2], v[3]);
    *(ushort4*)(Wt + (size_t)t * 8 + 4) = make_ushort4(v[4], v[5], v[6], v[7]);
}

// ---- phase 1: partition edges into dest-ranges; entry packed (row<<10)|li ----
__global__ __launch_bounds__(256) void k_part(const int* __restrict__ row,
                                              const int* __restrict__ col,
                                              int* __restrict__ binCursor,
                                              int* __restrict__ part, int E) {
    __shared__ int lcur[NBMAX], gbase[NBMAX];
    const int tid = threadIdx.x;
    const int e0 = blockIdx.x * PCH;
    const int cnt = min(PCH, E - e0);
    if (tid < NBMAX) lcur[tid] = 0;
    __syncthreads();
    int rr[8], cc[8], pp[8];
    if (cnt == PCH) {
#pragma unroll
        for (int h = 0; h < 2; h++) {
            const int4 c4 = *(const int4*)(col + e0 + h * 1024 + tid * 4);
            const int4 r4 = *(const int4*)(row + e0 + h * 1024 + tid * 4);
            cc[h * 4 + 0] = c4.x; cc[h * 4 + 1] = c4.y;
            cc[h * 4 + 2] = c4.z; cc[h * 4 + 3] = c4.w;
            rr[h * 4 + 0] = r4.x; rr[h * 4 + 1] = r4.y;
            rr[h * 4 + 2] = r4.z; rr[h * 4 + 3] = r4.w;
        }
    } else {
#pragma unroll
        for (int j = 0; j < 8; j++) {
            const int e = e0 + j * 256 + tid;
            if (e < e0 + cnt) { rr[j] = row[e]; cc[j] = col[e]; }
            else cc[j] = -1;
        }
    }
#pragma unroll
    for (int j = 0; j < 8; j++)
        if (cc[j] >= 0) pp[j] = atomicAdd(&lcur[cc[j] >> RB_SHIFT], 1);
    __syncthreads();
    if (tid < NBMAX && lcur[tid] > 0)
        gbase[tid] = atomicAdd(&binCursor[tid], lcur[tid]);
    __syncthreads();
#pragma unroll
    for (int j = 0; j < 8; j++)
        if (cc[j] >= 0)
            part[gbase[cc[j] >> RB_SHIFT] + pp[j]] =
                (rr[j] << RB_SHIFT) | (cc[j] & (RB - 1));
}

// ---- phase 2 (merged): per-range histogram + local scan + placement ----
__global__ __launch_bounds__(256) void k_csr(const int* __restrict__ binCursor,
                                             const int* __restrict__ part,
                                             int* __restrict__ degi,
                                             float* __restrict__ dinv,
                                             int* __restrict__ start,
                                             int* __restrict__ rs, int N) {
    __shared__ int cnt[RB];
    __shared__ int psum[256];
    const int b = blockIdx.x;
    const int lo = b << RB_SHIFT;
    const int tid = threadIdx.x;
    for (int i = tid; i < RB; i += 256) cnt[i] = 0;
    __syncthreads();
    const int base = b * MAXBIN;
    const int tot = binCursor[b] - base;
    for (int i = tid; i < tot; i += 256)
        atomicAdd(&cnt[part[base + i] & (RB - 1)], 1);
    __syncthreads();
    const int i0 = tid * 4;
    const int c0 = cnt[i0], c1 = cnt[i0 + 1], c2 = cnt[i0 + 2], c3 = cnt[i0 + 3];
    const int s = c0 + c1 + c2 + c3;
    psum[tid] = s;
    __syncthreads();
    for (int off = 1; off < 256; off <<= 1) {
        int t = (tid >= off) ? psum[tid - off] : 0;
        __syncthreads();
        psum[tid] += t;
        __syncthreads();
    }
    const int e = psum[tid] - s;   // exclusive
    const int offs[4] = {e, e + c0, e + c0 + c1, e + c0 + c1 + c2};
    const int cs[4] = {c0, c1, c2, c3};
#pragma unroll
    for (int j = 0; j < 4; j++) {
        const int n = lo + i0 + j;
        if (n < N) {
            degi[n] = cs[j];
            start[n] = base + offs[j];
            dinv[n] = cs[j] > 0 ? rsqrtf((float)cs[j]) : 0.f;
        }
        cnt[i0 + j] = base + offs[j];   // becomes LDS cursor
    }
    __syncthreads();
    for (int i = tid; i < tot; i += 256) {
        const int v = part[base + i];
        const int pos = atomicAdd(&cnt[v & (RB - 1)], 1);
        rs[pos] = v >> RB_SHIFT;
    }
}

// ---- layer-1 MFMA dual GEMM: x1 = relu(X@fcw+fcb) bf16, h1' = (X@c1w)*dinv bf16 ----
__global__ __launch_bounds__(256) void k_gemm1(const float* __restrict__ XF,
                                               const unsigned short* __restrict__ Wt,
                                               const float* __restrict__ B1,
                                               const float* __restrict__ dinv,
                                               unsigned short* __restrict__ O1b,
                                               unsigned short* __restrict__ O2,
                                               int N) {
    const int tid = threadIdx.x;
    const int wave = tid >> 6;
    const int lane = tid & 63;
    const int quad = lane >> 4;
    const int lm = lane & 15;
    const int n0 = blockIdx.x * 64 + wave * 16;
    if (n0 >= N) return;
    const int nrow = min(n0 + lm, N - 1);

    f32x4 acc[8];
#pragma unroll
    for (int c = 0; c < 8; c++) acc[c] = (f32x4){0.f, 0.f, 0.f, 0.f};

#pragma unroll
    for (int kc = 0; kc < 4; kc++) {
        const int k0 = kc * 32 + quad * 8;
        const float* s = XF + (size_t)nrow * IN_DIM + k0;
        const float4 q0 = *(const float4*)s;
        const float4 q1 = *(const float4*)(s + 4);
        bf16x8 a;
        a[0] = (short)f2bf(q0.x); a[1] = (short)f2bf(q0.y);
        a[2] = (short)f2bf(q0.z); a[3] = (short)f2bf(q0.w);
        a[4] = (short)f2bf(q1.x); a[5] = (short)f2bf(q1.y);
        a[6] = (short)f2bf(q1.z); a[7] = (short)f2bf(q1.w);
#pragma unroll
        for (int c = 0; c < 8; c++) {
            const bf16x8 b = *(const bf16x8*)(Wt + (size_t)((kc * 8 + c) * 64 + lane) * 8);
            acc[c] = __builtin_amdgcn_mfma_f32_16x16x32_bf16(a, b, acc[c], 0, 0, 0);
        }
    }

    const int nb = n0 + quad * 4;
    float dvv[4];
#pragma unroll
    for (int r = 0; r < 4; r++) dvv[r] = (nb + r < N) ? dinv[nb + r] : 0.f;
#pragma unroll
    for (int c = 0; c < 4; c++) {
        const int col = c * 16 + lm;
        const float b = B1[col];
#pragma unroll
        for (int r = 0; r < 4; r++) {
            const int n = nb + r;
            if (n < N) O1b[(size_t)n * 64 + col] = f2bf(relu(acc[c][r] + b));
        }
    }
#pragma unroll
    for (int c = 4; c < 8; c++) {
        const int col = (c - 4) * 16 + lm;
#pragma unroll
        for (int r = 0; r < 4; r++) {
            const int n = nb + r;
            if (n < N) O2[(size_t)n * 64 + col] = f2bf(acc[c][r] * dvv[r]);
        }
    }
}

#define ACC8(u)                                                          \
    a0 += bflo(u.x); a1 += bfhi(u.x); a2 += bflo(u.y); a3 += bfhi(u.y);  \
    a4 += bflo(u.z); a5 += bfhi(u.z); a6 += bflo(u.w); a7 += bfhi(u.w);

// ---- FUSED gather1 + gemm2, 128-thread blocks (16 dests) ----
// Round-12 structure (single dest per 8-lane group, unroll-4) but half-size
// blocks: finer scheduling granularity cuts the degree-imbalance tail
// (round-13 lesson: these gathers hide latency via wave count, not ILP).
__global__ __launch_bounds__(128) void k_gfuse(const int* __restrict__ start,
                                               const int* __restrict__ degi,
                                               const int* __restrict__ rs,
                                               const unsigned short* __restrict__ H,
                                               const float* __restrict__ dinv,
                                               const float* __restrict__ CB,
                                               const unsigned short* __restrict__ X1B,
                                               const unsigned short* __restrict__ Wt,
                                               const float* __restrict__ B1,
                                               unsigned short* __restrict__ X5B,
                                               unsigned short* __restrict__ H2,
                                               int N) {
    __shared__ __align__(16) unsigned short x2s[16][72];
    const int tid = threadIdx.x;
    const int l = tid & 7;                 // feats 8l..8l+7
    const int di = tid >> 3;               // 0..15 local dest
    const int d = blockIdx.x * 16 + di;

    uint4 ov = make_uint4(0u, 0u, 0u, 0u);
    if (d < N) {
        int s = start[d];
        const int e2 = s + degi[d];
        float a0 = 0.f, a1 = 0.f, a2 = 0.f, a3 = 0.f;
        float a4 = 0.f, a5 = 0.f, a6 = 0.f, a7 = 0.f;
        for (; s + 3 < e2; s += 4) {
            const int4 e4 = *(const int4*)(rs + s);
            const uint4 ua = *(const uint4*)(H + (size_t)e4.x * 64 + l * 8);
            const uint4 ub = *(const uint4*)(H + (size_t)e4.y * 64 + l * 8);
            const uint4 uc = *(const uint4*)(H + (size_t)e4.z * 64 + l * 8);
            const uint4 ud = *(const uint4*)(H + (size_t)e4.w * 64 + l * 8);
            ACC8(ua) ACC8(ub) ACC8(uc) ACC8(ud)
        }
        for (; s < e2; ++s) {
            const uint4 ua = *(const uint4*)(H + (size_t)rs[s] * 64 + l * 8);
            ACC8(ua)
        }
        const float dd = dinv[d];
        const float4 cba = *(const float4*)(CB + l * 8);
        const float4 cbb = *(const float4*)(CB + l * 8 + 4);
        ov.x = (unsigned)f2bf(relu(dd * a0 + cba.x)) |
               ((unsigned)f2bf(relu(dd * a1 + cba.y)) << 16);
        ov.y = (unsigned)f2bf(relu(dd * a2 + cba.z)) |
               ((unsigned)f2bf(relu(dd * a3 + cba.w)) << 16);
        ov.z = (unsigned)f2bf(relu(dd * a4 + cbb.x)) |
               ((unsigned)f2bf(relu(dd * a5 + cbb.y)) << 16);
        ov.w = (unsigned)f2bf(relu(dd * a6 + cbb.z)) |
               ((unsigned)f2bf(relu(dd * a7 + cbb.w)) << 16);
    }
    *(uint4*)&x2s[di][l * 8] = ov;
    __syncthreads();

    // phase B: 16-node tile; wave0 -> cols 0-63 (x5b), wave1 -> cols 64-127 (h2)
    const int wave = tid >> 6;             // 0..1
    const int lane = tid & 63;
    const int quad = lane >> 4;
    const int lm = lane & 15;
    const int cb4 = wave * 4;
    const int n0 = blockIdx.x * 16;
    if (n0 >= N) return;
    const int nrow = min(n0 + lm, N - 1);

    f32x4 acc[4];
#pragma unroll
    for (int c = 0; c < 4; c++) acc[c] = (f32x4){0.f, 0.f, 0.f, 0.f};
#pragma unroll
    for (int kc = 0; kc < 4; kc++) {
        bf16x8 a;
        if (kc < 2) {
            a = *(const bf16x8*)(X1B + (size_t)nrow * 64 + kc * 32 + quad * 8);
        } else {
            a = *(const bf16x8*)&x2s[lm][(kc - 2) * 32 + quad * 8];
        }
#pragma unroll
        for (int c = 0; c < 4; c++) {
            const bf16x8 b =
                *(const bf16x8*)(Wt + (size_t)((kc * 8 + cb4 + c) * 64 + lane) * 8);
            acc[c] = __builtin_amdgcn_mfma_f32_16x16x32_bf16(a, b, acc[c], 0, 0, 0);
        }
    }
    const int nb = n0 + quad * 4;
    if (cb4 == 0) {
#pragma unroll
        for (int c = 0; c < 4; c++) {
            const int col = c * 16 + lm;
            const float b = B1[col];
#pragma unroll
            for (int r = 0; r < 4; r++) {
                const int n = nb + r;
                if (n < N) X5B[(size_t)n * 64 + col] = f2bf(relu(acc[c][r] + b));
            }
        }
    } else {
        float dvv[4];
#pragma unroll
        for (int r = 0; r < 4; r++) dvv[r] = (nb + r < N) ? dinv[nb + r] : 0.f;
#pragma unroll
        for (int c = 0; c < 4; c++) {
            const int col = c * 16 + lm;
#pragma unroll
            for (int r = 0; r < 4; r++) {
                const int n = nb + r;
                if (n < N) H2[(size_t)n * 64 + col] = f2bf(acc[c][r] * dvv[r]);
            }
        }
    }
}

// ---- gather2 + fused combine/projections, 128-thread blocks (16 dests) ----
__global__ __launch_bounds__(128) void k_gather2(const int* __restrict__ start,
                                                 const int* __restrict__ degi,
                                                 const int* __restrict__ rs,
                                                 const unsigned short* __restrict__ H,
                                                 const float* __restrict__ dinv,
                                                 const float* __restrict__ CB,
                                                 const unsigned short* __restrict__ X5B,
                                                 const float* __restrict__ FC2W,
                                                 const float* __restrict__ FC2B,
                                                 const float* __restrict__ C3W,
                                                 const float* __restrict__ C3B,
                                                 float* __restrict__ H3,
                                                 float* __restrict__ OUT, int N) {
    const int l = threadIdx.x & 7;
    const int d = blockIdx.x * 16 + (threadIdx.x >> 3);
    if (d >= N) return;
    int s = start[d];
    const int e2 = s + degi[d];
    float a0 = 0.f, a1 = 0.f, a2 = 0.f, a3 = 0.f;
    float a4 = 0.f, a5 = 0.f, a6 = 0.f, a7 = 0.f;
    for (; s + 3 < e2; s += 4) {
        const int4 e4 = *(const int4*)(rs + s);
        const uint4 ua = *(const uint4*)(H + (size_t)e4.x * 64 + l * 8);
        const uint4 ub = *(const uint4*)(H + (size_t)e4.y * 64 + l * 8);
        const uint4 uc = *(const uint4*)(H + (size_t)e4.z * 64 + l * 8);
        const uint4 ud = *(const uint4*)(H + (size_t)e4.w * 64 + l * 8);
        ACC8(ua) ACC8(ub) ACC8(uc) ACC8(ud)
    }
    for (; s < e2; ++s) {
        const uint4 ua = *(const uint4*)(H + (size_t)rs[s] * 64 + l * 8);
        ACC8(ua)
    }
    const float dd = dinv[d];
    const float4 cba = *(const float4*)(CB + l * 8);
    const float4 cbb = *(const float4*)(CB + l * 8 + 4);
    const uint4 xv = *(const uint4*)(X5B + (size_t)d * 64 + l * 8);
    const float v0 = bflo(xv.x) + relu(dd * a0 + cba.x);
    const float v1 = bfhi(xv.x) + relu(dd * a1 + cba.y);
    const float v2 = bflo(xv.y) + relu(dd * a2 + cba.z);
    const float v3 = bfhi(xv.y) + relu(dd * a3 + cba.w);
    const float v4 = bflo(xv.z) + relu(dd * a4 + cbb.x);
    const float v5 = bfhi(xv.z) + relu(dd * a5 + cbb.y);
    const float v6 = bflo(xv.w) + relu(dd * a6 + cbb.z);
    const float v7 = bfhi(xv.w) + relu(dd * a7 + cbb.w);
    const float4 w9a = *(const float4*)(FC2W + l * 8);
    const float4 w9b = *(const float4*)(FC2W + l * 8 + 4);
    const float4 wXa = *(const float4*)(C3W + l * 8);
    const float4 wXb = *(const float4*)(C3W + l * 8 + 4);
    float p9 = v0 * w9a.x + v1 * w9a.y + v2 * w9a.z + v3 * w9a.w
             + v4 * w9b.x + v5 * w9b.y + v6 * w9b.z + v7 * w9b.w;
    float p10 = v0 * wXa.x + v1 * wXa.y + v2 * wXa.z + v3 * wXa.w
              + v4 * wXb.x + v5 * wXb.y + v6 * wXb.z + v7 * wXb.w;
#pragma unroll
    for (int m = 1; m < 8; m <<= 1) {
        p9 += __shfl_xor(p9, m, 64);
        p10 += __shfl_xor(p10, m, 64);
    }
    if (l == 0) {
        OUT[d] = p9 + FC2B[0] + C3B[0];
        H3[d] = p10 * dd;   // pre-scale by dinv[row] for gather1f
    }
}
#undef ACC8

// ---- final CSR gather, 1 feature (H3 pre-scaled; ×dinv[d] at end) ----
__global__ __launch_bounds__(256) void k_gather1f(const int* __restrict__ start,
                                                  const int* __restrict__ degi,
                                                  const int* __restrict__ rs,
                                                  const float* __restrict__ H3,
                                                  const float* __restrict__ dinv,
                                                  float* __restrict__ OUT, int N) {
    const int d = blockIdx.x * 256 + threadIdx.x;
    if (d >= N) return;
    int s = start[d];
    const int e2 = s + degi[d];
    float acc = 0.f;
    for (; s + 3 < e2; s += 4) {
        const int4 e4 = *(const int4*)(rs + s);
        acc += H3[e4.x] + H3[e4.y] + H3[e4.z] + H3[e4.w];
    }
    for (; s < e2; ++s) acc += H3[rs[s]];
    OUT[d] += acc * dinv[d];
}

extern "C" void kernel_launch(void* const* d_in, const int* in_sizes, int n_in,
                              void* d_out, int out_size, void* d_ws, size_t ws_size,
                              hipStream_t stream) {
    const float* x    = (const float*)d_in[0];
    const float* fcw  = (const float*)d_in[1];
    const float* fcb  = (const float*)d_in[2];
    const float* c1w  = (const float*)d_in[3];
    const float* c1b  = (const float*)d_in[4];
    const float* f1w  = (const float*)d_in[5];
    const float* f1b  = (const float*)d_in[6];
    const float* c2w  = (const float*)d_in[7];
    const float* c2b  = (const float*)d_in[8];
    const float* f2w  = (const float*)d_in[9];
    const float* f2b  = (const float*)d_in[10];
    const float* c3w  = (const float*)d_in[11];
    const float* c3b  = (const float*)d_in[12];
    const int*   ei   = (const int*)d_in[13];

    const int N = in_sizes[0] / IN_DIM;
    const int E = in_sizes[13] / 2;
    const int* row = ei;
    const int* col = ei + E;
    float* out = (float*)d_out;

    const int NR = (N + RB - 1) >> RB_SHIFT;

    const size_t Npad = ((size_t)N + 127) & ~(size_t)127;
    const size_t NF = (size_t)N * 64;
    const size_t REG = (size_t)NR * MAXBIN;
    int*   binCur = (int*)d_ws;                          // NBMAX
    int*   degi   = binCur + NBMAX;                      // N
    float* dinv   = (float*)(degi + Npad);               // N
    int*   start  = (int*)(dinv + Npad);                 // N
    unsigned short* Wt = (unsigned short*)(start + Npad);// 2*16384 bf16
    int*   part   = (int*)(Wt + 2 * 16384);              // REG int (packed)
    int*   rs     = part + REG;                          // REG int
    unsigned short* x1bf = (unsigned short*)(rs + REG);  // N*64 bf16
    unsigned short* h1   = x1bf + NF;                    // N*64 bf16
    unsigned short* h2   = h1 + NF;                      // N*64 bf16 (no alias: gfuse race)
    unsigned short* x5b  = h2 + NF;                      // N*64 bf16
    float* h3     = (float*)(x5b + NF);                  // N f32 (pre-scaled)

    const int gN = (N + 255) / 256;
    const int gG = (N + 63) / 64;
    const int gF = (N + 15) / 16;
    const int gP = (E + PCH - 1) / PCH;

    // --- CSR build + weight repack ---
    k_wprep<<<16, 256, 0, stream>>>(fcw, c1w, f1w, c2w, Wt, binCur, NR);
    k_part<<<gP, 256, 0, stream>>>(row, col, binCur, part, E);
    k_csr<<<NR, 256, 0, stream>>>(binCur, part, degi, dinv, start, rs, N);

    // --- layer 1 ---
    k_gemm1<<<gG, 256, 0, stream>>>(x, Wt, fcb, dinv, x1bf, h1, N);

    // --- gather1 + layer-2 GEMM fused (16 dests / 128-thread block) ---
    k_gfuse<<<gF, 128, 0, stream>>>(start, degi, rs, h1, dinv, c1b,
                                    x1bf, Wt + 16384, f1b, x5b, h2, N);

    // --- layer 3 (combine fused into gather2) ---
    k_gather2<<<gF, 128, 0, stream>>>(start, degi, rs, h2, dinv, c2b, x5b,
                                      f2w, f2b, c3w, c3b, h3, out, N);
    k_gather1f<<<gN, 256, 0, stream>>>(start, degi, rs, h3, dinv, out, N);
}